// Round 1
// baseline (576.048 us; speedup 1.0000x reference)
//
#include <hip/hip_runtime.h>

#define D 128
#define E_DIM 64

// ---------------------------------------------------------------------------
// Kernel 1: per-node score precompute.
// ns[n] = { h_n@Wu[:,0], h_n@Wu[:,1], h_n@Wv[:,0], h_n@Wv[:,1] }
// One 64-lane wave per node; each lane loads float2 of h (coalesced 512B/wave)
// ---------------------------------------------------------------------------
__global__ void node_score_kernel(const float* __restrict__ node_feats,
                                  const float* __restrict__ W,
                                  float4* __restrict__ ns,
                                  int n_nodes) {
    int wave = (blockIdx.x * blockDim.x + threadIdx.x) >> 6;
    int lane = threadIdx.x & 63;
    if (wave >= n_nodes) return;

    const float2 h = ((const float2*)(node_feats + (size_t)wave * D))[lane];
    const int r0 = lane * 2;
    const int r1 = lane * 2 + 1;
    // W is (2*D + E_DIM, 2) row-major; Wu rows [0,128), Wv rows [128,256)
    float p0 = h.x * W[r0 * 2 + 0]       + h.y * W[r1 * 2 + 0];
    float p1 = h.x * W[r0 * 2 + 1]       + h.y * W[r1 * 2 + 1];
    float p2 = h.x * W[(D + r0) * 2 + 0] + h.y * W[(D + r1) * 2 + 0];
    float p3 = h.x * W[(D + r0) * 2 + 1] + h.y * W[(D + r1) * 2 + 1];

    for (int off = 32; off > 0; off >>= 1) {
        p0 += __shfl_down(p0, off, 64);
        p1 += __shfl_down(p1, off, 64);
        p2 += __shfl_down(p2, off, 64);
        p3 += __shfl_down(p3, off, 64);
    }
    if (lane == 0) ns[wave] = make_float4(p0, p1, p2, p3);
}

// ---------------------------------------------------------------------------
// Kernel 2: per-edge. 16 lanes per edge; each lane loads one float4 of
// edge_feats (wave covers 4 edges = 1 KiB contiguous), reduce within the
// 16-lane group, lane 0 adds the gathered node scores + bias and writes.
// ---------------------------------------------------------------------------
__global__ void edge_score_kernel(const float* __restrict__ edge_feats,
                                  const int* __restrict__ src,
                                  const int* __restrict__ dst,
                                  const float* __restrict__ W,
                                  const float* __restrict__ b,
                                  const float4* __restrict__ ns,
                                  float* __restrict__ out,
                                  int n_edges) {
    int tid = blockIdx.x * blockDim.x + threadIdx.x;
    int e = tid >> 4;
    int l = tid & 15;
    if (e >= n_edges) return;

    const float4 ef = ((const float4*)edge_feats)[(size_t)e * (E_DIM / 4) + l];
    const int r = 2 * D + l * 4;   // We rows [256, 320)
    float p0 = ef.x * W[(r + 0) * 2 + 0] + ef.y * W[(r + 1) * 2 + 0]
             + ef.z * W[(r + 2) * 2 + 0] + ef.w * W[(r + 3) * 2 + 0];
    float p1 = ef.x * W[(r + 0) * 2 + 1] + ef.y * W[(r + 1) * 2 + 1]
             + ef.z * W[(r + 2) * 2 + 1] + ef.w * W[(r + 3) * 2 + 1];

    for (int m = 8; m > 0; m >>= 1) {
        p0 += __shfl_xor(p0, m, 16);
        p1 += __shfl_xor(p1, m, 16);
    }

    if (l == 0) {
        const float4 s = ns[src[e]];   // uses .x (Wu out0), .y (Wu out1)
        const float4 d = ns[dst[e]];   // uses .z (Wv out0), .w (Wv out1)
        float2 o;
        o.x = p0 + s.x + d.z + b[0];
        o.y = p1 + s.y + d.w + b[1];
        ((float2*)out)[e] = o;
    }
}

// ---------------------------------------------------------------------------
// Fallback (only if ws_size is too small for the 800 KB node-score table):
// one wave per edge, full gather of both node rows + edge row, 64-lane reduce.
// ---------------------------------------------------------------------------
__global__ void edge_fallback_kernel(const float* __restrict__ node_feats,
                                     const float* __restrict__ edge_feats,
                                     const int* __restrict__ src,
                                     const int* __restrict__ dst,
                                     const float* __restrict__ W,
                                     const float* __restrict__ b,
                                     float* __restrict__ out,
                                     int n_edges) {
    int wave = (blockIdx.x * blockDim.x + threadIdx.x) >> 6;
    int l = threadIdx.x & 63;
    if (wave >= n_edges) return;

    const float* hu = node_feats + (size_t)src[wave] * D;
    const float* hv = node_feats + (size_t)dst[wave] * D;
    const float u0 = hu[l], u1 = hu[l + 64];
    const float v0 = hv[l], v1 = hv[l + 64];
    const float e0 = edge_feats[(size_t)wave * E_DIM + l];

    float p0 = u0 * W[l * 2 + 0]         + u1 * W[(l + 64) * 2 + 0]
             + v0 * W[(128 + l) * 2 + 0] + v1 * W[(192 + l) * 2 + 0]
             + e0 * W[(256 + l) * 2 + 0];
    float p1 = u0 * W[l * 2 + 1]         + u1 * W[(l + 64) * 2 + 1]
             + v0 * W[(128 + l) * 2 + 1] + v1 * W[(192 + l) * 2 + 1]
             + e0 * W[(256 + l) * 2 + 1];

    for (int off = 32; off > 0; off >>= 1) {
        p0 += __shfl_down(p0, off, 64);
        p1 += __shfl_down(p1, off, 64);
    }
    if (l == 0) {
        float2 o;
        o.x = p0 + b[0];
        o.y = p1 + b[1];
        ((float2*)out)[wave] = o;
    }
}

extern "C" void kernel_launch(void* const* d_in, const int* in_sizes, int n_in,
                              void* d_out, int out_size, void* d_ws, size_t ws_size,
                              hipStream_t stream) {
    const float* node_feats = (const float*)d_in[0];
    const float* edge_feats = (const float*)d_in[1];
    const int*   src        = (const int*)d_in[2];
    const int*   dst        = (const int*)d_in[3];
    const float* W          = (const float*)d_in[4];
    const float* b          = (const float*)d_in[5];
    float*       out        = (float*)d_out;

    const int n_nodes = in_sizes[0] / D;
    const int n_edges = in_sizes[2];

    const size_t ns_bytes = (size_t)n_nodes * 4 * sizeof(float);

    if (ws_size >= ns_bytes) {
        float4* ns = (float4*)d_ws;
        // 4 nodes per 256-thread block (one wave each)
        int nblk1 = (n_nodes + 3) / 4;
        node_score_kernel<<<nblk1, 256, 0, stream>>>(node_feats, W, ns, n_nodes);
        // 16 edges per 256-thread block (16 lanes each)
        int nblk2 = (n_edges + 15) / 16;
        edge_score_kernel<<<nblk2, 256, 0, stream>>>(edge_feats, src, dst, W, b,
                                                     ns, out, n_edges);
    } else {
        // 4 edges per 256-thread block (one wave each)
        int nblk = (n_edges + 3) / 4;
        edge_fallback_kernel<<<nblk, 256, 0, stream>>>(node_feats, edge_feats,
                                                       src, dst, W, b, out, n_edges);
    }
}